// Round 7
// baseline (257.995 us; speedup 1.0000x reference)
//
#include <hip/hip_runtime.h>
#include <cmath>

#define IN_CH 128
#define OUT_CH 128
#define KDIM 512           // Z row: x(128) | sum(128) | mean(128) | max(128)
#define NGEMM 384          // W^T rows: permuted (colgroup, wavehalf, section, ocol16)
#define GBM 256            // fallback gemm rows per block
#define GBMP 384           // pipe gemm rows per block (r7 retile)
#define GBN 192            // gemm cols (W^T rows) per block
#define SLOT_B 49152       // pipe slot bytes: A 24K | Bhi 12K | Blo 12K
#define SLOT_US 24576
#define SB_SLOT_US 20480   // fallback single-buffer slot (A16K|B12K|B12K)
#define PIPE_LDS_BYTES (3 * SLOT_B)   // D=3 ring = 147456 B

typedef __attribute__((ext_vector_type(8))) short bfrag;   // 8 bf16 in 4 VGPRs
typedef __attribute__((ext_vector_type(4))) float f32x4;

// float -> bf16 round-to-nearest-even (bit pattern)
__device__ __forceinline__ unsigned short f2bf(float f) {
    unsigned int u = __float_as_uint(f);
    return (unsigned short)((u + 0x7FFFu + ((u >> 16) & 1u)) >> 16);
}
__device__ __forceinline__ float bf2f(unsigned short h) {
    return __uint_as_float(((unsigned int)h) << 16);
}
__device__ __forceinline__ float4 unpack4(uint2 u) {
    float4 r;
    r.x = __uint_as_float(u.x << 16);
    r.y = __uint_as_float(u.x & 0xFFFF0000u);
    r.z = __uint_as_float(u.y << 16);
    r.w = __uint_as_float(u.y & 0xFFFF0000u);
    return r;
}

// async 16B global->LDS (wave-level; LDS side is lane-linear base+lane*16)
__device__ __forceinline__ void gl2lds16(const void* g, void* l) {
    __builtin_amdgcn_global_load_lds(
        (const __attribute__((address_space(1))) unsigned int*)g,
        (__attribute__((address_space(3))) unsigned int*)l, 16, 0, 0);
}

// ---------------- prep: degree atomics + x->bf16 cast + logsum zero (fused) --------

__global__ __launch_bounds__(256) void prep_kernel(const int* __restrict__ ei,
                                                   int* __restrict__ degree,
                                                   float* __restrict__ logsum,
                                                   const float* __restrict__ x,
                                                   unsigned short* __restrict__ xb,
                                                   int E, int total4) {
    int i = blockIdx.x * 256 + threadIdx.x;
    if (i == 0) logsum[0] = 0.f;                  // completes before scan1 (stream order)
    if (i < E) atomicAdd(&degree[ei[E + i]], 1);
    if (i < total4) {
        float4 v = ((const float4*)x)[i];
        uint2 p;
        p.x = (unsigned)f2bf(v.x) | ((unsigned)f2bf(v.y) << 16);
        p.y = (unsigned)f2bf(v.z) | ((unsigned)f2bf(v.w) << 16);
        ((uint2*)xb)[i] = p;
    }
}

// ---------- device-wide exclusive scan, 2 phases ----------
__global__ __launch_bounds__(256) void scan1_kernel(const int* __restrict__ degree,
                                                    int* __restrict__ part,
                                                    float* __restrict__ logsum, int n) {
    int i = blockIdx.x * 256 + threadIdx.x;
    int d = (i < n) ? degree[i] : 0;
    float lg = (i < n) ? logf((float)d + 2.0f) : 0.f;   // == log1p(d+1)
    #pragma unroll
    for (int off = 32; off; off >>= 1) {
        d += __shfl_down(d, off);
        lg += __shfl_down(lg, off);
    }
    __shared__ int sd[4];
    __shared__ float sl[4];
    int wv = threadIdx.x >> 6;
    if ((threadIdx.x & 63) == 0) { sd[wv] = d; sl[wv] = lg; }
    __syncthreads();
    if (threadIdx.x == 0) {
        part[blockIdx.x] = (sd[0] + sd[1]) + (sd[2] + sd[3]);
        atomicAdd(&logsum[0], (sl[0] + sl[1]) + (sl[2] + sl[3]));
    }
}

__global__ __launch_bounds__(256) void scan3_kernel(const int* __restrict__ degree,
                                                    const int* __restrict__ part,
                                                    int* __restrict__ offsets,
                                                    int n, int E, int Sb) {
    int tid = threadIdx.x;
    int i = blockIdx.x * 256 + tid;
    int b = blockIdx.x;
    int acc0 = 0;
    for (int j = tid; j < b; j += 256) acc0 += part[j];
    #pragma unroll
    for (int off = 32; off; off >>= 1) acc0 += __shfl_down(acc0, off);
    __shared__ int bsum[4];
    int lane = tid & 63, wv = tid >> 6;
    if (lane == 0) bsum[wv] = acc0;
    __syncthreads();
    int base = (bsum[0] + bsum[1]) + (bsum[2] + bsum[3]);

    int d = (i < n) ? degree[i] : 0;
    int s = d;
    #pragma unroll
    for (int off = 1; off < 64; off <<= 1) {
        int t = __shfl_up(s, off);
        if (lane >= off) s += t;
    }
    __shared__ int wsum[4];
    if (lane == 63) wsum[wv] = s;
    __syncthreads();
    for (int w2 = 0; w2 < wv; ++w2) base += wsum[w2];
    if (i < n) offsets[i] = base + s - d;             // exclusive prefix
    if (i == n - 1) offsets[n] = E;                   // Σ degree == E
}

// fill bumps offsets[] in place; afterwards offsets[v] == end of v's segment.
__global__ void fill_kernel(const int* __restrict__ ei, int* __restrict__ offsets,
                            int* __restrict__ csr_src, int E) {
    int e = blockIdx.x * blockDim.x + threadIdx.x;
    if (e < E) {
        int src = ei[e];
        int dst = ei[E + e];
        int pos = atomicAdd(&offsets[dst], 1);
        csr_src[pos] = src;
    }
}

// ---------------- Aggregation: one WAVE per node, bf16 edge-pair gathers ---------

__global__ __launch_bounds__(256) void agg_kernel(const unsigned short* __restrict__ xb,
                                                  const int* __restrict__ csr_src,
                                                  const int* __restrict__ offsets,
                                                  const int* __restrict__ degree,
                                                  const float* __restrict__ logsum,
                                                  unsigned short* __restrict__ Zhi,
                                                  float* __restrict__ ampv,
                                                  float* __restrict__ attv,
                                                  int N, int Mpad) {
    int node = (blockIdx.x * 256 + threadIdx.x) >> 6;
    int lane = threadIdx.x & 63;
    if (node >= Mpad) return;
    int h = lane >> 5;
    int c4 = lane & 31;
    long zbase = (long)node * KDIM + c4 * 4;
    if (node >= N) {   // pad rows: zero so GEMM reads are harmless
        if (h == 0) {
            uint2 z = make_uint2(0u, 0u);
            #pragma unroll
            for (int sec = 0; sec < 4; ++sec) *(uint2*)&Zhi[zbase + sec * 128] = z;
        }
        return;
    }
    int deg = degree[node];
    int end = offsets[node];          // post-fill end of segment
    int beg = end - deg;
    const float NEG = -3.402823466e38f;
    float4 s[4], m[4];
    #pragma unroll
    for (int u = 0; u < 4; ++u) {
        s[u] = make_float4(0.f, 0.f, 0.f, 0.f);
        m[u] = make_float4(NEG, NEG, NEG, NEG);
    }
    int i = beg;
    for (; i + 8 <= end; i += 8) {      // 4 pair-slots = 8 edges, 4 indep chains
        int idx[4];
        #pragma unroll
        for (int u = 0; u < 4; ++u) idx[u] = csr_src[i + u * 2 + h];
        uint2 raw[4];
        #pragma unroll
        for (int u = 0; u < 4; ++u) raw[u] = *(const uint2*)&xb[(long)idx[u] * IN_CH + c4 * 4];
        #pragma unroll
        for (int u = 0; u < 4; ++u) {
            float4 v = unpack4(raw[u]);
            s[u].x += v.x; s[u].y += v.y; s[u].z += v.z; s[u].w += v.w;
            m[u].x = fmaxf(m[u].x, v.x); m[u].y = fmaxf(m[u].y, v.y);
            m[u].z = fmaxf(m[u].z, v.z); m[u].w = fmaxf(m[u].w, v.w);
        }
    }
    for (; i < end; i += 2) {           // tail pairs (upper half may be inactive)
        int e = i + h;
        if (e < end) {
            float4 v = unpack4(*(const uint2*)&xb[(long)csr_src[e] * IN_CH + c4 * 4]);
            s[0].x += v.x; s[0].y += v.y; s[0].z += v.z; s[0].w += v.w;
            m[0].x = fmaxf(m[0].x, v.x); m[0].y = fmaxf(m[0].y, v.y);
            m[0].z = fmaxf(m[0].z, v.z); m[0].w = fmaxf(m[0].w, v.w);
        }
    }
    float4 sum, mx;
    sum.x = (s[0].x + s[1].x) + (s[2].x + s[3].x);
    sum.y = (s[0].y + s[1].y) + (s[2].y + s[3].y);
    sum.z = (s[0].z + s[1].z) + (s[2].z + s[3].z);
    sum.w = (s[0].w + s[1].w) + (s[2].w + s[3].w);
    mx.x = fmaxf(fmaxf(m[0].x, m[1].x), fmaxf(m[2].x, m[3].x));
    mx.y = fmaxf(fmaxf(m[0].y, m[1].y), fmaxf(m[2].y, m[3].y));
    mx.z = fmaxf(fmaxf(m[0].z, m[1].z), fmaxf(m[2].z, m[3].z));
    mx.w = fmaxf(fmaxf(m[0].w, m[1].w), fmaxf(m[2].w, m[3].w));
    // cross-half combine
    sum.x += __shfl_xor(sum.x, 32); sum.y += __shfl_xor(sum.y, 32);
    sum.z += __shfl_xor(sum.z, 32); sum.w += __shfl_xor(sum.w, 32);
    mx.x = fmaxf(mx.x, __shfl_xor(mx.x, 32)); mx.y = fmaxf(mx.y, __shfl_xor(mx.y, 32));
    mx.z = fmaxf(mx.z, __shfl_xor(mx.z, 32)); mx.w = fmaxf(mx.w, __shfl_xor(mx.w, 32));

    float inv = 1.0f / fmaxf((float)deg, 1.0f);
    float4 mean = make_float4(sum.x * inv, sum.y * inv, sum.z * inv, sum.w * inv);
    if (deg == 0) mx = make_float4(0.f, 0.f, 0.f, 0.f);
    float4 xv = unpack4(*(const uint2*)&xb[(long)node * IN_CH + c4 * 4]);

    if (h == 0) {
        float4 secs[4] = { xv, sum, mean, mx };
        #pragma unroll
        for (int sec = 0; sec < 4; ++sec) {
            float4 v = secs[sec];
            uint2 hi;
            hi.x = (unsigned)f2bf(v.x) | ((unsigned)f2bf(v.y) << 16);
            hi.y = (unsigned)f2bf(v.z) | ((unsigned)f2bf(v.w) << 16);
            *(uint2*)&Zhi[zbase + sec * 128] = hi;
        }
    }
    if (lane == 0) {
        float ref = fmaxf(logsum[0] / (float)N, 1.0f);
        float dt = log1pf((float)deg + 1.0f);
        ampv[node] = dt / ref;
        attv[node] = ref / fmaxf(dt, 1e-6f);
    }
}

// ---------------- Weight build: permuted row-major W^T, bf16 hi/lo -----------------

__global__ void wbuild_kernel(const float* __restrict__ Wmsg, const float* __restrict__ Wroot,
                              unsigned short* __restrict__ Whi, unsigned short* __restrict__ Wlo) {
    int idx = blockIdx.x * 256 + threadIdx.x;
    if (idx >= NGEMM * KDIM) return;
    int jp = idx >> 9;       // 0..383
    int k = idx & 511;
    int cg = jp / 96;
    int rem = jp - cg * 96;
    int s16 = rem >> 4;
    int r16 = rem & 15;
    int wn2 = s16 / 3;
    int sec = s16 - wn2 * 3;
    int ocol = cg * 32 + wn2 * 16 + r16;
    float v;
    if (k < 128) {
        v = (sec == 0) ? Wroot[ocol * 128 + k] : 0.f;
    } else {
        int a = (k - 128) >> 7;
        int c = (k - 128) & 127;
        v = Wmsg[ocol * 1152 + (a * 3 + sec) * 128 + c];
    }
    unsigned short h = f2bf(v);
    Whi[idx] = h;
    Wlo[idx] = f2bf(v - bf2f(h));
}

// ---------------- MFMA GEMM: GBM=384 retile (r7: cut staged bytes 21%) -------------
// Theory: gemm time = staged bytes / ~4.4 TB/s delivery cap (window>=2). Retile
// 256->384 rows/block: blocks 392->264 (near-perfect packing), B re-staging
// 150->100 MB. Same proven D=3 / counted-vmcnt / raw-barrier schedule.
// 16 waves: wm=w>>2 covers 96 rows (6 mt), wn=w&3 covers 48 cols (3 sections).
// Staging (uniform 3 gl2lds/wave/stage): w<8 -> A groups 3w..3w+2 (24 x 1KB);
// w>=8 -> B chunks 3(w-8)..3(w-8)+2 (hi 0-11, lo 12-23).
// Slot: A [0,24K) group g at g*1024+lane*16 | B [24K,48K) chunk c at c*1024+lane*16.

__global__ __launch_bounds__(1024, 4) void gemm_pipe(const unsigned short* __restrict__ Zhi,
                                                     const unsigned short* __restrict__ Whi,
                                                     const unsigned short* __restrict__ Wlo,
                                                     const float* __restrict__ ampv,
                                                     const float* __restrict__ attv,
                                                     const float* __restrict__ bmsg,
                                                     const float* __restrict__ broot,
                                                     float* __restrict__ out, int M) {
    extern __shared__ char smem[];
    unsigned short* lds = (unsigned short*)smem;
    const int tid = threadIdx.x;
    const int w = tid >> 6;                 // 0..15
    const int lane = tid & 63;
    const int r16 = lane & 15, q = lane >> 4;
    const int wm = w >> 2, wn = w & 3;
    const int row0 = blockIdx.x * GBMP;
    const int cg2 = blockIdx.y;             // 0..1

    // staging pointers: 3 gl2lds per wave per stage, uniform
    const unsigned short* sP0;
    int dd0;
    if (w < 8) {
        sP0 = Zhi + (long)(row0 + (3 * w) * 16 + r16) * KDIM + q * 8;
        dd0 = (3 * w) * 1024 + lane * 16;
    } else {
        const int c0 = 3 * (w - 8);                    // 0,3,..,21
        const unsigned short* Wb = (w < 12) ? Whi : Wlo;
        const int rr = (w < 12) ? c0 * 16 : (c0 - 12) * 16;
        sP0 = Wb + (long)(cg2 * GBN + rr + r16) * KDIM + q * 8;
        dd0 = 24576 + c0 * 1024 + lane * 16;
    }
    const unsigned short* sP1 = sP0 + 16 * KDIM;
    const unsigned short* sP2 = sP0 + 32 * KDIM;
    const int dd1 = dd0 + 1024, dd2 = dd0 + 2048;

    // prologue: stage 0 -> slot 0, stage 1 -> slot 1
    gl2lds16(sP0, smem + dd0); gl2lds16(sP1, smem + dd1); gl2lds16(sP2, smem + dd2);
    sP0 += 32; sP1 += 32; sP2 += 32;
    gl2lds16(sP0, smem + SLOT_B + dd0); gl2lds16(sP1, smem + SLOT_B + dd1);
    gl2lds16(sP2, smem + SLOT_B + dd2);
    sP0 += 32; sP1 += 32; sP2 += 32;

    __builtin_amdgcn_s_waitcnt(0x0F73);      // vmcnt(3): stage 0 landed (6 -> 3)
    __builtin_amdgcn_s_barrier();
    __builtin_amdgcn_sched_barrier(0);

    f32x4 acc[6][3] = {};
    const int jtb = (wn >> 1) * 6 + (wn & 1) * 3;

    #pragma unroll 1
    for (int it = 0; it < 16; ++it) {
        const int s = it % 3;
        if (it + 2 < 16) {                   // fire stage it+2
            char* b = smem + ((it + 2) % 3) * SLOT_B;
            gl2lds16(sP0, b + dd0); gl2lds16(sP1, b + dd1); gl2lds16(sP2, b + dd2);
            sP0 += 32; sP1 += 32; sP2 += 32;
        }
        const unsigned short* L = lds + s * SLOT_US;

        bfrag bh[3], bl[3];
        #pragma unroll
        for (int nt = 0; nt < 3; ++nt) {
            int chb = (jtb + nt) * 512 + lane * 8;
            bh[nt] = *(const bfrag*)&L[12288 + chb];    // B hi at us 12288
            bl[nt] = *(const bfrag*)&L[18432 + chb];    // B lo at us 18432
        }
        #pragma unroll
        for (int mt = 0; mt < 6; ++mt) {
            bfrag ah = *(const bfrag*)&L[((wm * 6 + mt) * 64 + lane) * 8];
            #pragma unroll
            for (int nt = 0; nt < 3; ++nt) {
                acc[mt][nt] = __builtin_amdgcn_mfma_f32_16x16x32_bf16(ah, bh[nt], acc[mt][nt], 0, 0, 0);
                acc[mt][nt] = __builtin_amdgcn_mfma_f32_16x16x32_bf16(ah, bl[nt], acc[mt][nt], 0, 0, 0);
            }
        }

        if (it < 14)       __builtin_amdgcn_s_waitcnt(0x0F73);  // vmcnt(3): stage it+1 landed
        else if (it == 14) __builtin_amdgcn_s_waitcnt(0x0F70);  // vmcnt(0): stage 15 landed
        if (it < 15) {
            __builtin_amdgcn_s_barrier();
            __builtin_amdgcn_sched_barrier(0);
        }
    }

    // fused epilogue: C/D layout col=lane&15, row=q*4+r (verified m89/m91)
    const int col = (cg2 * 2 + (wn >> 1)) * 32 + (wn & 1) * 16 + r16;
    const float bias = bmsg[col] + broot[col];
    #pragma unroll
    for (int mt = 0; mt < 6; ++mt) {
        #pragma unroll
        for (int r = 0; r < 4; ++r) {
            int row = row0 + wm * 96 + mt * 16 + q * 4 + r;
            if (row < M) {
                float v = acc[mt][0][r]
                        + ampv[row] * acc[mt][1][r]
                        + attv[row] * acc[mt][2][r] + bias;
                out[(long)row * OUT_CH + col] = v;
            }
        }
    }
}

// ---------------- fallback: single-buffer (static 40 KB), 16-wave GBM=256 ----------

__global__ __launch_bounds__(1024, 4) void gemm_sb(const unsigned short* __restrict__ Zhi,
                                                   const unsigned short* __restrict__ Whi,
                                                   const unsigned short* __restrict__ Wlo,
                                                   const float* __restrict__ ampv,
                                                   const float* __restrict__ attv,
                                                   const float* __restrict__ bmsg,
                                                   const float* __restrict__ broot,
                                                   float* __restrict__ out, int M) {
    __shared__ unsigned short lds[SB_SLOT_US];   // 40 KB
    const int tid = threadIdx.x;
    const int w = tid >> 6;
    const int lane = tid & 63;
    const int r16 = lane & 15, q = lane >> 4;
    const int wm = w >> 2, wn = w & 3;
    const int row0 = blockIdx.x * GBM;
    const int cg2 = blockIdx.y;

    const unsigned short* sAh = Zhi + (long)(row0 + w * 16 + r16) * KDIM + q * 8;
    const unsigned short* sB2 = (w < 12)
        ? Whi + (long)(cg2 * GBN + w * 16 + r16) * KDIM + q * 8
        : Wlo + (long)(cg2 * GBN + (w - 12) * 16 + r16) * KDIM + q * 8;
    const unsigned short* sB3 = Wlo + (long)(cg2 * GBN + (4 + w) * 16 + r16) * KDIM + q * 8;
    char* ldsb = (char*)lds;
    const int d0 = tid * 16, d2 = (1024 + tid) * 16, d3 = (2048 + tid) * 16;

    f32x4 acc[4][3] = {};
    const int jtb = (wn >> 1) * 6 + (wn & 1) * 3;

    #pragma unroll 1
    for (int it = 0; it < 16; ++it) {
        if (it) __syncthreads();
        gl2lds16(sAh, ldsb + d0); gl2lds16(sB2, ldsb + d2); if (w < 8) gl2lds16(sB3, ldsb + d3);
        sAh += 32; sB2 += 32; sB3 += 32;
        __syncthreads();

        bfrag bh[3], bl[3];
        #pragma unroll
        for (int nt = 0; nt < 3; ++nt) {
            int chb = (jtb + nt) * 512 + lane * 8;
            bh[nt] = *(const bfrag*)&lds[8192 + chb];
            bl[nt] = *(const bfrag*)&lds[14336 + chb];
        }
        #pragma unroll
        for (int mt = 0; mt < 4; ++mt) {
            bfrag ah = *(const bfrag*)&lds[((wm * 4 + mt) * 64 + lane) * 8];
            #pragma unroll
            for (int nt = 0; nt < 3; ++nt) {
                acc[mt][nt] = __builtin_amdgcn_mfma_f32_16x16x32_bf16(ah, bh[nt], acc[mt][nt], 0, 0, 0);
                acc[mt][nt] = __builtin_amdgcn_mfma_f32_16x16x32_bf16(ah, bl[nt], acc[mt][nt], 0, 0, 0);
            }
        }
    }

    const int col = (cg2 * 2 + (wn >> 1)) * 32 + (wn & 1) * 16 + r16;
    const float bias = bmsg[col] + broot[col];
    #pragma unroll
    for (int mt = 0; mt < 4; ++mt) {
        #pragma unroll
        for (int r = 0; r < 4; ++r) {
            int row = row0 + wm * 64 + mt * 16 + q * 4 + r;
            if (row < M) {
                float v = acc[mt][0][r]
                        + ampv[row] * acc[mt][1][r]
                        + attv[row] * acc[mt][2][r] + bias;
                out[(long)row * OUT_CH + col] = v;
            }
        }
    }
}

// ---------------- Launch ----------------

extern "C" void kernel_launch(void* const* d_in, const int* in_sizes, int n_in,
                              void* d_out, int out_size, void* d_ws, size_t ws_size,
                              hipStream_t stream) {
    const float* x     = (const float*)d_in[0];
    const int*   ei    = (const int*)d_in[1];
    const float* Wmsg  = (const float*)d_in[2];
    const float* bmsg  = (const float*)d_in[3];
    const float* Wroot = (const float*)d_in[4];
    const float* broot = (const float*)d_in[5];
    float* out = (float*)d_out;

    int N = in_sizes[0] / IN_CH;           // 50000
    int E = in_sizes[1] / 2;               // 600000
    int Mb768 = (N + 767) / 768;           // 66
    int Mpad = Mb768 * 768;                // 50688 (divisible by 256 and 384)
    int MbP = Mpad / GBMP;                 // 132 pipe blocks
    int MbS = Mpad / GBM;                  // 198 fallback blocks
    int Sb = (N + 255) / 256;              // scan blocks (196)
    int total4 = N * IN_CH / 4;

    char* ws = (char*)d_ws;
    size_t off = 0;
    auto alloc = [&](size_t bytes) -> void* {
        void* p = ws + off;
        off = (off + bytes + 255) & ~(size_t)255;
        return p;
    };
    int* degree  = (int*)alloc((size_t)N * 4);
    int* offsets = (int*)alloc((size_t)(N + 1) * 4);
    float* logsum = (float*)alloc(4);
    int* part    = (int*)alloc((size_t)Sb * 4);
    int* csr_src = (int*)alloc((size_t)E * 4);
    unsigned short* Whi = (unsigned short*)alloc((size_t)NGEMM * KDIM * 2);
    unsigned short* Wlo = (unsigned short*)alloc((size_t)NGEMM * KDIM * 2);
    unsigned short* Zhi = (unsigned short*)alloc((size_t)Mpad * KDIM * 2);
    unsigned short* xb  = (unsigned short*)alloc((size_t)Mpad * IN_CH * 2);
    float* ampv = (float*)alloc((size_t)N * 4);
    float* attv = (float*)alloc((size_t)N * 4);

    hipMemsetAsync(degree, 0, (size_t)N * 4, stream);

    int prepg = (max(E, total4) + 255) / 256;
    prep_kernel<<<prepg, 256, 0, stream>>>(ei, degree, logsum, x, xb, E, total4);
    scan1_kernel<<<Sb, 256, 0, stream>>>(degree, part, logsum, N);
    scan3_kernel<<<Sb, 256, 0, stream>>>(degree, part, offsets, N, E, Sb);
    fill_kernel<<<(E + 255) / 256, 256, 0, stream>>>(ei, offsets, csr_src, E);
    agg_kernel<<<(Mpad * 64 + 255) / 256, 256, 0, stream>>>(xb, csr_src, offsets, degree, logsum,
                                                            Zhi, ampv, attv, N, Mpad);
    wbuild_kernel<<<(NGEMM * KDIM + 255) / 256, 256, 0, stream>>>(Wmsg, Wroot, Whi, Wlo);

    // device-capability branch (deterministic per device; capture-safe host queries)
    bool pipe = false;
    int dev = 0;
    if (hipGetDevice(&dev) == hipSuccess) {
        int optin = 0;
        if (hipDeviceGetAttribute(&optin, hipDeviceAttributeSharedMemPerBlockOptin, dev) == hipSuccess
            && optin >= (int)PIPE_LDS_BYTES) {
            pipe = (hipFuncSetAttribute((const void*)gemm_pipe,
                                        hipFuncAttributeMaxDynamicSharedMemorySize,
                                        PIPE_LDS_BYTES) == hipSuccess);
        }
    }
    if (pipe) {
        dim3 ggrid(MbP, 2);
        gemm_pipe<<<ggrid, 1024, PIPE_LDS_BYTES, stream>>>(Zhi, Whi, Wlo, ampv, attv,
                                                           bmsg, broot, out, N);
    } else {
        dim3 ggrid(MbS, 2);
        gemm_sb<<<ggrid, 1024, 0, stream>>>(Zhi, Whi, Wlo, ampv, attv,
                                            bmsg, broot, out, N);
    }
}

// Round 8
// 232.428 us; speedup vs baseline: 1.1100x; 1.1100x over previous
//
#include <hip/hip_runtime.h>
#include <cmath>

#define IN_CH 128
#define OUT_CH 128
#define KDIM 512           // Z row: x(128) | sum(128) | mean(128) | max(128)
#define NGEMM 384          // W^T rows: permuted (colgroup, wavehalf, section, ocol16)
#define GBM 256            // fallback gemm rows per block
#define GBMP 448           // pipe gemm rows per block (r8: single-round packing)
#define GBN 192            // gemm cols (W^T rows) per block
#define SLOT_B 53248       // pipe slot bytes: A 28K | Bhi 12K | Blo 12K
#define SLOT_US 26624
#define SB_SLOT_US 20480   // fallback single-buffer slot (A16K|B12K|B12K)
#define PIPE_LDS_BYTES (3 * SLOT_B)   // D=3 ring = 159744 B <= 160 KiB

typedef __attribute__((ext_vector_type(8))) short bfrag;   // 8 bf16 in 4 VGPRs
typedef __attribute__((ext_vector_type(4))) float f32x4;

// float -> bf16 round-to-nearest-even (bit pattern)
__device__ __forceinline__ unsigned short f2bf(float f) {
    unsigned int u = __float_as_uint(f);
    return (unsigned short)((u + 0x7FFFu + ((u >> 16) & 1u)) >> 16);
}
__device__ __forceinline__ float bf2f(unsigned short h) {
    return __uint_as_float(((unsigned int)h) << 16);
}
__device__ __forceinline__ float4 unpack4(uint2 u) {
    float4 r;
    r.x = __uint_as_float(u.x << 16);
    r.y = __uint_as_float(u.x & 0xFFFF0000u);
    r.z = __uint_as_float(u.y << 16);
    r.w = __uint_as_float(u.y & 0xFFFF0000u);
    return r;
}

// async 16B global->LDS (wave-level; LDS side is lane-linear base+lane*16)
__device__ __forceinline__ void gl2lds16(const void* g, void* l) {
    __builtin_amdgcn_global_load_lds(
        (const __attribute__((address_space(1))) unsigned int*)g,
        (__attribute__((address_space(3))) unsigned int*)l, 16, 0, 0);
}

// ---------------- prep: degree atomics + x->bf16 cast + logsum zero (fused) --------

__global__ __launch_bounds__(256) void prep_kernel(const int* __restrict__ ei,
                                                   int* __restrict__ degree,
                                                   float* __restrict__ logsum,
                                                   const float* __restrict__ x,
                                                   unsigned short* __restrict__ xb,
                                                   int E, int total4) {
    int i = blockIdx.x * 256 + threadIdx.x;
    if (i == 0) logsum[0] = 0.f;                  // completes before scan1 (stream order)
    if (i < E) atomicAdd(&degree[ei[E + i]], 1);
    if (i < total4) {
        float4 v = ((const float4*)x)[i];
        uint2 p;
        p.x = (unsigned)f2bf(v.x) | ((unsigned)f2bf(v.y) << 16);
        p.y = (unsigned)f2bf(v.z) | ((unsigned)f2bf(v.w) << 16);
        ((uint2*)xb)[i] = p;
    }
}

// ---------- device-wide exclusive scan, 2 phases ----------
__global__ __launch_bounds__(256) void scan1_kernel(const int* __restrict__ degree,
                                                    int* __restrict__ part,
                                                    float* __restrict__ logsum, int n) {
    int i = blockIdx.x * 256 + threadIdx.x;
    int d = (i < n) ? degree[i] : 0;
    float lg = (i < n) ? logf((float)d + 2.0f) : 0.f;   // == log1p(d+1)
    #pragma unroll
    for (int off = 32; off; off >>= 1) {
        d += __shfl_down(d, off);
        lg += __shfl_down(lg, off);
    }
    __shared__ int sd[4];
    __shared__ float sl[4];
    int wv = threadIdx.x >> 6;
    if ((threadIdx.x & 63) == 0) { sd[wv] = d; sl[wv] = lg; }
    __syncthreads();
    if (threadIdx.x == 0) {
        part[blockIdx.x] = (sd[0] + sd[1]) + (sd[2] + sd[3]);
        atomicAdd(&logsum[0], (sl[0] + sl[1]) + (sl[2] + sl[3]));
    }
}

__global__ __launch_bounds__(256) void scan3_kernel(const int* __restrict__ degree,
                                                    const int* __restrict__ part,
                                                    int* __restrict__ offsets,
                                                    int n, int E, int Sb) {
    int tid = threadIdx.x;
    int i = blockIdx.x * 256 + tid;
    int b = blockIdx.x;
    int acc0 = 0;
    for (int j = tid; j < b; j += 256) acc0 += part[j];
    #pragma unroll
    for (int off = 32; off; off >>= 1) acc0 += __shfl_down(acc0, off);
    __shared__ int bsum[4];
    int lane = tid & 63, wv = tid >> 6;
    if (lane == 0) bsum[wv] = acc0;
    __syncthreads();
    int base = (bsum[0] + bsum[1]) + (bsum[2] + bsum[3]);

    int d = (i < n) ? degree[i] : 0;
    int s = d;
    #pragma unroll
    for (int off = 1; off < 64; off <<= 1) {
        int t = __shfl_up(s, off);
        if (lane >= off) s += t;
    }
    __shared__ int wsum[4];
    if (lane == 63) wsum[wv] = s;
    __syncthreads();
    for (int w2 = 0; w2 < wv; ++w2) base += wsum[w2];
    if (i < n) offsets[i] = base + s - d;             // exclusive prefix
    if (i == n - 1) offsets[n] = E;                   // Σ degree == E
}

// fill bumps offsets[] in place; afterwards offsets[v] == end of v's segment.
__global__ void fill_kernel(const int* __restrict__ ei, int* __restrict__ offsets,
                            int* __restrict__ csr_src, int E) {
    int e = blockIdx.x * blockDim.x + threadIdx.x;
    if (e < E) {
        int src = ei[e];
        int dst = ei[E + e];
        int pos = atomicAdd(&offsets[dst], 1);
        csr_src[pos] = src;
    }
}

// ---------------- Aggregation: one WAVE per node, bf16 edge-pair gathers ---------

__global__ __launch_bounds__(256) void agg_kernel(const unsigned short* __restrict__ xb,
                                                  const int* __restrict__ csr_src,
                                                  const int* __restrict__ offsets,
                                                  const int* __restrict__ degree,
                                                  const float* __restrict__ logsum,
                                                  unsigned short* __restrict__ Zhi,
                                                  float* __restrict__ ampv,
                                                  float* __restrict__ attv,
                                                  int N, int Mpad) {
    int node = (blockIdx.x * 256 + threadIdx.x) >> 6;
    int lane = threadIdx.x & 63;
    if (node >= Mpad) return;
    int h = lane >> 5;
    int c4 = lane & 31;
    long zbase = (long)node * KDIM + c4 * 4;
    if (node >= N) {   // pad rows: zero so GEMM reads are harmless
        if (h == 0) {
            uint2 z = make_uint2(0u, 0u);
            #pragma unroll
            for (int sec = 0; sec < 4; ++sec) *(uint2*)&Zhi[zbase + sec * 128] = z;
        }
        return;
    }
    int deg = degree[node];
    int end = offsets[node];          // post-fill end of segment
    int beg = end - deg;
    const float NEG = -3.402823466e38f;
    float4 s[4], m[4];
    #pragma unroll
    for (int u = 0; u < 4; ++u) {
        s[u] = make_float4(0.f, 0.f, 0.f, 0.f);
        m[u] = make_float4(NEG, NEG, NEG, NEG);
    }
    int i = beg;
    for (; i + 8 <= end; i += 8) {      // 4 pair-slots = 8 edges, 4 indep chains
        int idx[4];
        #pragma unroll
        for (int u = 0; u < 4; ++u) idx[u] = csr_src[i + u * 2 + h];
        uint2 raw[4];
        #pragma unroll
        for (int u = 0; u < 4; ++u) raw[u] = *(const uint2*)&xb[(long)idx[u] * IN_CH + c4 * 4];
        #pragma unroll
        for (int u = 0; u < 4; ++u) {
            float4 v = unpack4(raw[u]);
            s[u].x += v.x; s[u].y += v.y; s[u].z += v.z; s[u].w += v.w;
            m[u].x = fmaxf(m[u].x, v.x); m[u].y = fmaxf(m[u].y, v.y);
            m[u].z = fmaxf(m[u].z, v.z); m[u].w = fmaxf(m[u].w, v.w);
        }
    }
    for (; i < end; i += 2) {           // tail pairs (upper half may be inactive)
        int e = i + h;
        if (e < end) {
            float4 v = unpack4(*(const uint2*)&xb[(long)csr_src[e] * IN_CH + c4 * 4]);
            s[0].x += v.x; s[0].y += v.y; s[0].z += v.z; s[0].w += v.w;
            m[0].x = fmaxf(m[0].x, v.x); m[0].y = fmaxf(m[0].y, v.y);
            m[0].z = fmaxf(m[0].z, v.z); m[0].w = fmaxf(m[0].w, v.w);
        }
    }
    float4 sum, mx;
    sum.x = (s[0].x + s[1].x) + (s[2].x + s[3].x);
    sum.y = (s[0].y + s[1].y) + (s[2].y + s[3].y);
    sum.z = (s[0].z + s[1].z) + (s[2].z + s[3].z);
    sum.w = (s[0].w + s[1].w) + (s[2].w + s[3].w);
    mx.x = fmaxf(fmaxf(m[0].x, m[1].x), fmaxf(m[2].x, m[3].x));
    mx.y = fmaxf(fmaxf(m[0].y, m[1].y), fmaxf(m[2].y, m[3].y));
    mx.z = fmaxf(fmaxf(m[0].z, m[1].z), fmaxf(m[2].z, m[3].z));
    mx.w = fmaxf(fmaxf(m[0].w, m[1].w), fmaxf(m[2].w, m[3].w));
    // cross-half combine
    sum.x += __shfl_xor(sum.x, 32); sum.y += __shfl_xor(sum.y, 32);
    sum.z += __shfl_xor(sum.z, 32); sum.w += __shfl_xor(sum.w, 32);
    mx.x = fmaxf(mx.x, __shfl_xor(mx.x, 32)); mx.y = fmaxf(mx.y, __shfl_xor(mx.y, 32));
    mx.z = fmaxf(mx.z, __shfl_xor(mx.z, 32)); mx.w = fmaxf(mx.w, __shfl_xor(mx.w, 32));

    float inv = 1.0f / fmaxf((float)deg, 1.0f);
    float4 mean = make_float4(sum.x * inv, sum.y * inv, sum.z * inv, sum.w * inv);
    if (deg == 0) mx = make_float4(0.f, 0.f, 0.f, 0.f);
    float4 xv = unpack4(*(const uint2*)&xb[(long)node * IN_CH + c4 * 4]);

    if (h == 0) {
        float4 secs[4] = { xv, sum, mean, mx };
        #pragma unroll
        for (int sec = 0; sec < 4; ++sec) {
            float4 v = secs[sec];
            uint2 hi;
            hi.x = (unsigned)f2bf(v.x) | ((unsigned)f2bf(v.y) << 16);
            hi.y = (unsigned)f2bf(v.z) | ((unsigned)f2bf(v.w) << 16);
            *(uint2*)&Zhi[zbase + sec * 128] = hi;
        }
    }
    if (lane == 0) {
        float ref = fmaxf(logsum[0] / (float)N, 1.0f);
        float dt = log1pf((float)deg + 1.0f);
        ampv[node] = dt / ref;
        attv[node] = ref / fmaxf(dt, 1e-6f);
    }
}

// ---------------- Weight build: permuted row-major W^T, bf16 hi/lo -----------------

__global__ void wbuild_kernel(const float* __restrict__ Wmsg, const float* __restrict__ Wroot,
                              unsigned short* __restrict__ Whi, unsigned short* __restrict__ Wlo) {
    int idx = blockIdx.x * 256 + threadIdx.x;
    if (idx >= NGEMM * KDIM) return;
    int jp = idx >> 9;       // 0..383
    int k = idx & 511;
    int cg = jp / 96;
    int rem = jp - cg * 96;
    int s16 = rem >> 4;
    int r16 = rem & 15;
    int wn2 = s16 / 3;
    int sec = s16 - wn2 * 3;
    int ocol = cg * 32 + wn2 * 16 + r16;
    float v;
    if (k < 128) {
        v = (sec == 0) ? Wroot[ocol * 128 + k] : 0.f;
    } else {
        int a = (k - 128) >> 7;
        int c = (k - 128) & 127;
        v = Wmsg[ocol * 1152 + (a * 3 + sec) * 128 + c];
    }
    unsigned short h = f2bf(v);
    Whi[idx] = h;
    Wlo[idx] = f2bf(v - bf2f(h));
}

// ---------------- MFMA GEMM: GBM=448, single-round grid (r8) -----------------------
// r7 lesson: per-row cost improved with bigger tile, but 264 blocks at 1 block/CU
// = 256+8 -> full second round (51% util). GBM=448: 112x2 = 224 blocks <= 256 CUs
// -> ONE round. Slot: A 28K (28 chunks) | B 24K (24 chunks hi/lo); D=3 = 159744 B.
// Staging: 52 chunks/stage; waves 0-11 carry 3 (L=3), waves 12-15 carry 4 (L=4).
// Same proven schedule: fire stage it+2, counted vmcnt(L) (window 2), raw barrier.
// Chunk c: c<28 -> A rows 16c..16c+15; c>=28 -> B chunk c-28 (hi 0-11, lo 12-23).
// LDS: chunk c at byte c*1024 + lane*16. Wave tile: wm=w>>2 -> 112 rows (7 mt),
// wn=w&3 -> 48 cols (3 sections). acc[7][3].

__global__ __launch_bounds__(1024, 4) void gemm_pipe(const unsigned short* __restrict__ Zhi,
                                                     const unsigned short* __restrict__ Whi,
                                                     const unsigned short* __restrict__ Wlo,
                                                     const float* __restrict__ ampv,
                                                     const float* __restrict__ attv,
                                                     const float* __restrict__ bmsg,
                                                     const float* __restrict__ broot,
                                                     float* __restrict__ out, int M) {
    extern __shared__ char smem[];
    unsigned short* lds = (unsigned short*)smem;
    const int tid = threadIdx.x;
    const int w = tid >> 6;                 // 0..15
    const int lane = tid & 63;
    const int r16 = lane & 15, q = lane >> 4;
    const int wm = w >> 2, wn = w & 3;
    const int row0 = blockIdx.x * GBMP;
    const int cg2 = blockIdx.y;             // 0..1
    const bool four = (w >= 12);

    // staging chunks: waves 0-11 -> chunks 3w..3w+2; waves 12-15 -> 36+4(w-12)..+3
    const int cbase = four ? (36 + 4 * (w - 12)) : (3 * w);
    const unsigned short* sP[4];
    int dd[4];
    #pragma unroll
    for (int j = 0; j < 4; ++j) {
        int c = cbase + ((four || j < 3) ? j : 0);      // j=3 unused for w<12
        if (c < 28) {
            sP[j] = Zhi + (long)(row0 + c * 16 + r16) * KDIM + q * 8;
        } else {
            int b = c - 28;
            const unsigned short* Wb = (b < 12) ? Whi : Wlo;
            int rr = (b < 12) ? b * 16 : (b - 12) * 16;
            sP[j] = Wb + (long)(cg2 * GBN + rr + r16) * KDIM + q * 8;
        }
        dd[j] = c * 1024 + lane * 16;
    }

    // prologue: stage 0 -> slot 0, stage 1 -> slot 1
    #pragma unroll
    for (int p = 0; p < 2; ++p) {
        char* b = smem + p * SLOT_B;
        gl2lds16(sP[0], b + dd[0]); gl2lds16(sP[1], b + dd[1]); gl2lds16(sP[2], b + dd[2]);
        if (four) gl2lds16(sP[3], b + dd[3]);
        #pragma unroll
        for (int j = 0; j < 4; ++j) sP[j] += 32;
    }

    if (four) __builtin_amdgcn_s_waitcnt(0x0F74);   // vmcnt(4): stage 0 landed (8->4)
    else      __builtin_amdgcn_s_waitcnt(0x0F73);   // vmcnt(3): (6->3)
    __builtin_amdgcn_s_barrier();
    __builtin_amdgcn_sched_barrier(0);

    f32x4 acc[7][3] = {};
    const int jtb = (wn >> 1) * 6 + (wn & 1) * 3;

    #pragma unroll 1
    for (int it = 0; it < 16; ++it) {
        const int s = it % 3;
        if (it + 2 < 16) {                   // fire stage it+2
            char* b = smem + ((it + 2) % 3) * SLOT_B;
            gl2lds16(sP[0], b + dd[0]); gl2lds16(sP[1], b + dd[1]); gl2lds16(sP[2], b + dd[2]);
            if (four) gl2lds16(sP[3], b + dd[3]);
            #pragma unroll
            for (int j = 0; j < 4; ++j) sP[j] += 32;
        }
        const unsigned short* L = lds + s * SLOT_US;

        bfrag bh[3], bl[3];
        #pragma unroll
        for (int nt = 0; nt < 3; ++nt) {
            int chb = (jtb + nt) * 512 + lane * 8;
            bh[nt] = *(const bfrag*)&L[14336 + chb];    // B hi: chunks 0-11
            bl[nt] = *(const bfrag*)&L[20480 + chb];    // B lo: chunks 12-23
        }
        #pragma unroll
        for (int mt = 0; mt < 7; ++mt) {
            bfrag ah = *(const bfrag*)&L[((wm * 7 + mt) * 64 + lane) * 8];
            #pragma unroll
            for (int nt = 0; nt < 3; ++nt) {
                acc[mt][nt] = __builtin_amdgcn_mfma_f32_16x16x32_bf16(ah, bh[nt], acc[mt][nt], 0, 0, 0);
                acc[mt][nt] = __builtin_amdgcn_mfma_f32_16x16x32_bf16(ah, bl[nt], acc[mt][nt], 0, 0, 0);
            }
        }

        if (it < 14) {                       // own stage(it+1) landed
            if (four) __builtin_amdgcn_s_waitcnt(0x0F74);
            else      __builtin_amdgcn_s_waitcnt(0x0F73);
        } else if (it == 14) {
            __builtin_amdgcn_s_waitcnt(0x0F70);          // vmcnt(0): stage 15 landed
        }
        if (it < 15) {
            __builtin_amdgcn_s_barrier();
            __builtin_amdgcn_sched_barrier(0);
        }
    }

    // fused epilogue: C/D layout col=lane&15, row=q*4+r (verified m89/m91)
    const int col = (cg2 * 2 + (wn >> 1)) * 32 + (wn & 1) * 16 + r16;
    const float bias = bmsg[col] + broot[col];
    #pragma unroll
    for (int mt = 0; mt < 7; ++mt) {
        #pragma unroll
        for (int r = 0; r < 4; ++r) {
            int row = row0 + wm * 112 + mt * 16 + q * 4 + r;
            if (row < M) {
                float v = acc[mt][0][r]
                        + ampv[row] * acc[mt][1][r]
                        + attv[row] * acc[mt][2][r] + bias;
                out[(long)row * OUT_CH + col] = v;
            }
        }
    }
}

// ---------------- fallback: single-buffer (static 40 KB), 16-wave GBM=256 ----------

__global__ __launch_bounds__(1024, 4) void gemm_sb(const unsigned short* __restrict__ Zhi,
                                                   const unsigned short* __restrict__ Whi,
                                                   const unsigned short* __restrict__ Wlo,
                                                   const float* __restrict__ ampv,
                                                   const float* __restrict__ attv,
                                                   const float* __restrict__ bmsg,
                                                   const float* __restrict__ broot,
                                                   float* __restrict__ out, int M) {
    __shared__ unsigned short lds[SB_SLOT_US];   // 40 KB
    const int tid = threadIdx.x;
    const int w = tid >> 6;
    const int lane = tid & 63;
    const int r16 = lane & 15, q = lane >> 4;
    const int wm = w >> 2, wn = w & 3;
    const int row0 = blockIdx.x * GBM;
    const int cg2 = blockIdx.y;

    const unsigned short* sAh = Zhi + (long)(row0 + w * 16 + r16) * KDIM + q * 8;
    const unsigned short* sB2 = (w < 12)
        ? Whi + (long)(cg2 * GBN + w * 16 + r16) * KDIM + q * 8
        : Wlo + (long)(cg2 * GBN + (w - 12) * 16 + r16) * KDIM + q * 8;
    const unsigned short* sB3 = Wlo + (long)(cg2 * GBN + (4 + w) * 16 + r16) * KDIM + q * 8;
    char* ldsb = (char*)lds;
    const int d0 = tid * 16, d2 = (1024 + tid) * 16, d3 = (2048 + tid) * 16;

    f32x4 acc[4][3] = {};
    const int jtb = (wn >> 1) * 6 + (wn & 1) * 3;

    #pragma unroll 1
    for (int it = 0; it < 16; ++it) {
        if (it) __syncthreads();
        gl2lds16(sAh, ldsb + d0); gl2lds16(sB2, ldsb + d2); if (w < 8) gl2lds16(sB3, ldsb + d3);
        sAh += 32; sB2 += 32; sB3 += 32;
        __syncthreads();

        bfrag bh[3], bl[3];
        #pragma unroll
        for (int nt = 0; nt < 3; ++nt) {
            int chb = (jtb + nt) * 512 + lane * 8;
            bh[nt] = *(const bfrag*)&lds[8192 + chb];
            bl[nt] = *(const bfrag*)&lds[14336 + chb];
        }
        #pragma unroll
        for (int mt = 0; mt < 4; ++mt) {
            bfrag ah = *(const bfrag*)&lds[((wm * 4 + mt) * 64 + lane) * 8];
            #pragma unroll
            for (int nt = 0; nt < 3; ++nt) {
                acc[mt][nt] = __builtin_amdgcn_mfma_f32_16x16x32_bf16(ah, bh[nt], acc[mt][nt], 0, 0, 0);
                acc[mt][nt] = __builtin_amdgcn_mfma_f32_16x16x32_bf16(ah, bl[nt], acc[mt][nt], 0, 0, 0);
            }
        }
    }

    const int col = (cg2 * 2 + (wn >> 1)) * 32 + (wn & 1) * 16 + r16;
    const float bias = bmsg[col] + broot[col];
    #pragma unroll
    for (int mt = 0; mt < 4; ++mt) {
        #pragma unroll
        for (int r = 0; r < 4; ++r) {
            int row = row0 + wm * 64 + mt * 16 + q * 4 + r;
            if (row < M) {
                float v = acc[mt][0][r]
                        + ampv[row] * acc[mt][1][r]
                        + attv[row] * acc[mt][2][r] + bias;
                out[(long)row * OUT_CH + col] = v;
            }
        }
    }
}

// ---------------- Launch ----------------

extern "C" void kernel_launch(void* const* d_in, const int* in_sizes, int n_in,
                              void* d_out, int out_size, void* d_ws, size_t ws_size,
                              hipStream_t stream) {
    const float* x     = (const float*)d_in[0];
    const int*   ei    = (const int*)d_in[1];
    const float* Wmsg  = (const float*)d_in[2];
    const float* bmsg  = (const float*)d_in[3];
    const float* Wroot = (const float*)d_in[4];
    const float* broot = (const float*)d_in[5];
    float* out = (float*)d_out;

    int N = in_sizes[0] / IN_CH;           // 50000
    int E = in_sizes[1] / 2;               // 600000
    int Mpad = 50176;                      // = 112*448 = 196*256 (N<=50176 fixed shape)
    if (N > Mpad) Mpad = ((N + 447) / 448) * 448;   // safety for other shapes
    int MbP = (Mpad + GBMP - 1) / GBMP;    // 112 pipe blocks
    int MbS = (Mpad + GBM - 1) / GBM;      // 196 fallback blocks
    int Sb = (N + 255) / 256;              // scan blocks (196)
    int total4 = N * IN_CH / 4;

    char* ws = (char*)d_ws;
    size_t off = 0;
    auto alloc = [&](size_t bytes) -> void* {
        void* p = ws + off;
        off = (off + bytes + 255) & ~(size_t)255;
        return p;
    };
    size_t MpadA = (size_t)MbP * GBMP;     // allocation rows (>= Mpad)
    if ((size_t)MbS * GBM > MpadA) MpadA = (size_t)MbS * GBM;
    int* degree  = (int*)alloc((size_t)N * 4);
    int* offsets = (int*)alloc((size_t)(N + 1) * 4);
    float* logsum = (float*)alloc(4);
    int* part    = (int*)alloc((size_t)Sb * 4);
    int* csr_src = (int*)alloc((size_t)E * 4);
    unsigned short* Whi = (unsigned short*)alloc((size_t)NGEMM * KDIM * 2);
    unsigned short* Wlo = (unsigned short*)alloc((size_t)NGEMM * KDIM * 2);
    unsigned short* Zhi = (unsigned short*)alloc(MpadA * KDIM * 2);
    unsigned short* xb  = (unsigned short*)alloc(MpadA * IN_CH * 2);
    float* ampv = (float*)alloc((size_t)N * 4);
    float* attv = (float*)alloc((size_t)N * 4);
    int MpadZ = (int)MpadA;                // rows to zero-pad in agg

    hipMemsetAsync(degree, 0, (size_t)N * 4, stream);

    int prepg = (max(E, total4) + 255) / 256;
    prep_kernel<<<prepg, 256, 0, stream>>>(ei, degree, logsum, x, xb, E, total4);
    scan1_kernel<<<Sb, 256, 0, stream>>>(degree, part, logsum, N);
    scan3_kernel<<<Sb, 256, 0, stream>>>(degree, part, offsets, N, E, Sb);
    fill_kernel<<<(E + 255) / 256, 256, 0, stream>>>(ei, offsets, csr_src, E);
    agg_kernel<<<(MpadZ * 64 + 255) / 256, 256, 0, stream>>>(xb, csr_src, offsets, degree, logsum,
                                                             Zhi, ampv, attv, N, MpadZ);
    wbuild_kernel<<<(NGEMM * KDIM + 255) / 256, 256, 0, stream>>>(Wmsg, Wroot, Whi, Wlo);

    // device-capability branch (deterministic per device; capture-safe host queries)
    bool pipe = false;
    int dev = 0;
    if (hipGetDevice(&dev) == hipSuccess) {
        int optin = 0;
        if (hipDeviceGetAttribute(&optin, hipDeviceAttributeSharedMemPerBlockOptin, dev) == hipSuccess
            && optin >= (int)PIPE_LDS_BYTES) {
            pipe = (hipFuncSetAttribute((const void*)gemm_pipe,
                                        hipFuncAttributeMaxDynamicSharedMemorySize,
                                        PIPE_LDS_BYTES) == hipSuccess);
        }
    }
    if (pipe) {
        dim3 ggrid(MbP, 2);
        gemm_pipe<<<ggrid, 1024, PIPE_LDS_BYTES, stream>>>(Zhi, Whi, Wlo, ampv, attv,
                                                           bmsg, broot, out, N);
    } else {
        dim3 ggrid(MbS, 2);
        gemm_sb<<<ggrid, 1024, 0, stream>>>(Zhi, Whi, Wlo, ampv, attv,
                                            bmsg, broot, out, N);
    }
}